// Round 1
// baseline (1620.946 us; speedup 1.0000x reference)
//
#include <hip/hip_runtime.h>

// Markonv: out[b,n,p] = sum_{l,ij} x[b,i,p+l]*x[b,j,p+l+1] * W[l,i,j,n]
// B=128, C=4, L=10000, K=20, N=128, stride=1, P=9980.
// Strategy: bf16 MFMA (32x32x16), B(W)-stationary in registers, pair tile in LDS.
// Roofline: 654 MB fp32 output write => ~104 us floor; bf16 MFMA compute ~44 us.

#define B_    128
#define C_    4
#define L_    10000
#define K_    20
#define N_    128
#define P_    9980          // floor((L-1-K)/1)+1
#define MT    64            // output rows (positions) per tile iteration
#define ROWS  (MT + K_ - 1) // 83 pair rows per tile
#define TPG   13            // tiles per workgroup
#define GRPS  12            // tile-groups per batch: 12*13*64 = 9984 >= 9980

typedef float  f32x16 __attribute__((ext_vector_type(16)));
typedef float  f32x4v __attribute__((ext_vector_type(4)));
typedef __bf16 bf16x8 __attribute__((ext_vector_type(8)));
typedef unsigned short u16x8 __attribute__((ext_vector_type(8)));

static __device__ __forceinline__ unsigned short f2bf(float f) {
  union { float f; unsigned u; } v; v.f = f;
  unsigned r = (v.u + 0x7fffu + ((v.u >> 16) & 1u)) >> 16;
  return (unsigned short)r;
}

// Repack W[l][i][j][n] fp32 -> Wb[l][n][ij] bf16 (B-fragment friendly: 16
// contiguous bf16 per (l,n) row = one 16B half per lane-half).
__global__ void convW_kernel(const float* __restrict__ W,
                             unsigned short* __restrict__ Wb) {
  int idx = blockIdx.x * 256 + threadIdx.x;          // [l][n][ij]
  if (idx < K_ * N_ * 16) {
    int ij = idx & 15, n = (idx >> 4) & (N_ - 1), l = idx >> 11;
    Wb[idx] = f2bf(W[(l * 16 + ij) * N_ + n]);
  }
}

__launch_bounds__(256, 2)
__global__ void markonv_kernel(const float* __restrict__ x,
                               const unsigned short* __restrict__ Wb,
                               const float* __restrict__ Wf,
                               float* __restrict__ out,
                               int useGather) {
  // LDS: x slab (4 channels x 84 positions) + pair tile (83 rows x 16 ch bf16)
  __shared__ __align__(16) float xs[C_][MT + 24];              // 84 used
  __shared__ __align__(16) unsigned short pairLds[ROWS * 16];  // 32 B rows, dense

  const int tid  = threadIdx.x;
  const int lane = tid & 63;
  const int wid  = tid >> 6;        // 0..3
  const int mb   = wid >> 1;        // wave's 32-row block within 64-row tile
  const int nh   = wid & 1;         // wave's 64-col half of N
  const int h    = lane >> 5;       // k-half
  const int nl   = lane & 31;       // n within 32-block / m within 32-block
  const int b    = blockIdx.y;
  const int grp  = blockIdx.x;

  // ---- Load W fragments once per workgroup (held in VGPRs: 20*2*4 = 160) ----
  bf16x8 bfr[K_][2];
  if (useGather) {
    // fallback: gather straight from fp32 W (ws too small) — slower, correct
    #pragma unroll
    for (int l = 0; l < K_; ++l) {
      #pragma unroll
      for (int nb = 0; nb < 2; ++nb) {
        int n = nh * 64 + nb * 32 + nl;
        u16x8 u;
        #pragma unroll
        for (int j = 0; j < 8; ++j)
          u[j] = f2bf(Wf[(l * 16 + 8 * h + j) * N_ + n]);
        bfr[l][nb] = __builtin_bit_cast(bf16x8, u);
      }
    }
  } else {
    #pragma unroll
    for (int l = 0; l < K_; ++l) {
      #pragma unroll
      for (int nb = 0; nb < 2; ++nb) {
        int n = nh * 64 + nb * 32 + nl;
        bfr[l][nb] = __builtin_bit_cast(bf16x8,
            *(const u16x8*)(Wb + ((l * N_ + n) * 16 + 8 * h)));
      }
    }
  }

  const float* xrow = x + (size_t)(b * C_ + wid) * L_;  // wave wid owns channel wid

  #pragma unroll 1
  for (int it = 0; it < TPG; ++it) {
    const int tile = grp * TPG + it;
    const int t0   = tile * MT;     // base transition/position index

    __syncthreads();                // pairLds/xs no longer read by prev iter
    // ---- stage x: xs[c][u] = x[b,c,t0+u], u in [0,84) ----
    {
      int t = t0 + lane;
      xs[wid][lane] = (t < L_) ? xrow[t] : 0.f;
      if (lane < (ROWS + 1 - 64)) {                       // lane < 20
        int t2 = t0 + 64 + lane;
        xs[wid][64 + lane] = (t2 < L_) ? xrow[t2] : 0.f;
      }
    }
    __syncthreads();
    // ---- build pair tile: pair[r][i*4+j] = x[i][r]*x[j][r+1] (bf16) ----
    if (tid < ROWS) {
      int r = tid;
      #pragma unroll
      for (int i = 0; i < C_; ++i) {
        float xi = xs[i][r];
        #pragma unroll
        for (int j = 0; j < C_; ++j)
          pairLds[r * 16 + i * 4 + j] = f2bf(xi * xs[j][r + 1]);
      }
    }
    __syncthreads();

    // ---- K loop: 20 x (1 ds_read_b128 + 2 mfma) ----
    f32x16 acc[2];
    #pragma unroll
    for (int i = 0; i < 16; ++i) { acc[0][i] = 0.f; acc[1][i] = 0.f; }

    const int arow = mb * 32 + nl;  // A row (lane's m) within pair tile
    #pragma unroll
    for (int l = 0; l < K_; ++l) {
      bf16x8 af = __builtin_bit_cast(bf16x8,
          *(const u16x8*)&pairLds[(arow + l) * 16 + 8 * h]);
      acc[0] = __builtin_amdgcn_mfma_f32_32x32x16_bf16(af, bfr[l][0], acc[0], 0, 0, 0);
      acc[1] = __builtin_amdgcn_mfma_f32_32x32x16_bf16(af, bfr[l][1], acc[1], 0, 0, 0);
    }

    // ---- epilogue: C/D row = (reg&3) + 8*(reg>>2) + 4*h -> regs 4q..4q+3 are
    //      4 consecutive positions => aligned float4 nontemporal stores ----
    #pragma unroll
    for (int nb = 0; nb < 2; ++nb) {
      int n = nh * 64 + nb * 32 + nl;
      float* orow = out + (size_t)(b * N_ + n) * P_;
      #pragma unroll
      for (int q = 0; q < 4; ++q) {
        int pv = t0 + mb * 32 + 4 * h + 8 * q;
        if (pv < P_) {
          f32x4v v = { acc[nb][4 * q], acc[nb][4 * q + 1],
                       acc[nb][4 * q + 2], acc[nb][4 * q + 3] };
          __builtin_nontemporal_store(v, (f32x4v*)(orow + pv));
        }
      }
    }
  }
}

extern "C" void kernel_launch(void* const* d_in, const int* in_sizes, int n_in,
                              void* d_out, int out_size, void* d_ws, size_t ws_size,
                              hipStream_t stream) {
  const float* x  = (const float*)d_in[0];
  const float* W  = (const float*)d_in[1];
  float* out      = (float*)d_out;

  const size_t wbBytes = (size_t)K_ * N_ * 16 * sizeof(unsigned short); // 80 KB
  int useGather = (ws_size < wbBytes || d_ws == nullptr) ? 1 : 0;
  unsigned short* Wb = (unsigned short*)d_ws;

  if (!useGather) {
    convW_kernel<<<dim3((K_ * N_ * 16 + 255) / 256), dim3(256), 0, stream>>>(W, Wb);
  }
  markonv_kernel<<<dim3(GRPS, B_), dim3(256), 0, stream>>>(x, Wb, W, out, useGather);
}